// Round 9
// baseline (1134.108 us; speedup 1.0000x reference)
//
#include <hip/hip_runtime.h>
#include <hip/hip_bf16.h>
#include <hip/hip_cooperative_groups.h>
#include <math.h>

namespace cg = cooperative_groups;

typedef __attribute__((ext_vector_type(8))) short short8;
typedef __attribute__((ext_vector_type(4))) float floatx4;
typedef __attribute__((ext_vector_type(4))) short short4v;
typedef __attribute__((ext_vector_type(2))) unsigned int uint2v;

#define D_MODEL 1024
#define N_HEADS 16
#define DK 64
#define D_FF 4096
#define BB 4
#define SS 2048
#define NTOK (BB * SS) /* 8192 */
#define LN_EPS 1e-5f
#define SCL 0.18033688011112042f /* 0.125 * log2(e), folded into Wq/bq */
#define NBLK 768                 /* 3 blocks/CU x 256 CU */

static __device__ __forceinline__ short f2bf(float f) {
  union { float f; unsigned int u; } v;
  v.f = f;
  unsigned int u = v.u;
  unsigned int r = u + 0x7fffu + ((u >> 16) & 1u);
  return (short)(r >> 16);
}

#define GLL16(g, l)                                                            \
  __builtin_amdgcn_global_load_lds(                                            \
      (const __attribute__((address_space(1))) void*)(g),                      \
      (__attribute__((address_space(3))) void*)(l), 16, 0, 0)

// ================= device stage helpers (shared by mega + fallback) ==========

__device__ __forceinline__ void dev_ln_row(int row, const float* x,
                                           const float* g, const float* b,
                                           short* out, char* smem) {
  float* red = (float*)smem;
  int t = threadIdx.x;
  const float4* rp = (const float4*)(x + (size_t)row * D_MODEL);
  float4 v = rp[t];
  float s = v.x + v.y + v.z + v.w;
  float ss = v.x * v.x + v.y * v.y + v.z * v.z + v.w * v.w;
#pragma unroll
  for (int off = 32; off >= 1; off >>= 1) {
    s += __shfl_xor(s, off, 64);
    ss += __shfl_xor(ss, off, 64);
  }
  int wv = t >> 6;
  if ((t & 63) == 0) { red[wv] = s; red[wv + 4] = ss; }
  __syncthreads();
  s = red[0] + red[1] + red[2] + red[3];
  ss = red[4] + red[5] + red[6] + red[7];
  float mu = s * (1.0f / D_MODEL);
  float var = ss * (1.0f / D_MODEL) - mu * mu;
  float rstd = rsqrtf(var + LN_EPS);
  float4 gv = ((const float4*)g)[t];
  float4 bv = ((const float4*)b)[t];
  short4v o;
  o.x = f2bf((v.x - mu) * rstd * gv.x + bv.x);
  o.y = f2bf((v.y - mu) * rstd * gv.y + bv.y);
  o.z = f2bf((v.z - mu) * rstd * gv.z + bv.z);
  o.w = f2bf((v.w - mu) * rstd * gv.w + bv.w);
  *(short4v*)(out + (size_t)row * D_MODEL + t * 4) = o;
}

__device__ __forceinline__ void dev_wconv(
    int id, const float* Wq, const float* Wk, const float* Wv, const float* Wo,
    const float* W1, const float* W2, const float* bq, const float* bk,
    const float* bv, short* wqkv_t, short* wo_t, short* w1_t, short* w2_t,
    float* bqkv, char* smem) {
  int t = threadIdx.x;
  if (id == 3072) {
    for (int i = t; i < 1024; i += 256) {
      bqkv[i] = bq[i] * SCL;
      bqkv[1024 + i] = bk[i];
      bqkv[2048 + i] = bv[i];
    }
    return;
  }
  float (*tile)[65] = (float (*)[65])smem;
  const float* W;
  short* Wt;
  int K, N, tid;
  float scale = 1.0f;
  if (id < 1024) {
    int wsel = id >> 8;
    tid = id & 255;
    K = 1024; N = 1024;
    W = wsel == 0 ? Wq : wsel == 1 ? Wk : wsel == 2 ? Wv : Wo;
    Wt = wsel < 3 ? wqkv_t + (size_t)wsel * 1024 * 1024 : wo_t;
    if (wsel == 0) scale = SCL;
  } else if (id < 2048) {
    tid = id - 1024; K = 1024; N = 4096; W = W1; Wt = w1_t;
  } else {
    tid = id - 2048; K = 4096; N = 1024; W = W2; Wt = w2_t;
  }
  int ntn = N >> 6;
  int n0 = (tid % ntn) * 64, k0 = (tid / ntn) * 64;
  int c = t & 63, r0 = t >> 6;
#pragma unroll
  for (int i = 0; i < 16; i++) {
    int r = r0 + i * 4;
    tile[r][c] = W[(size_t)(k0 + r) * N + n0 + c];
  }
  __syncthreads();
#pragma unroll
  for (int i = 0; i < 16; i++) {
    int r = r0 + i * 4;
    Wt[(size_t)(n0 + r) * K + k0 + c] = f2bf(tile[c][r] * scale);
  }
}

// One 128x128 GEMM tile: C = A x Bt + bias (BK=64, swizzled, GLL16).
template <int MODE>
__device__ __forceinline__ void dev_gemm_tile(
    const short* A, const short* Bt, const float* bias, const float* res,
    float* outf, short* outb, int N, int K, int m0, int n0, char* smem) {
  short* As = (short*)smem;
  short* Bs = As + 128 * 64;
  int t = threadIdx.x;
  int w = t >> 6, l = t & 63;
  int lm = l & 15, lq = l >> 4;
  floatx4 acc[4][4] = {};
  int l3 = l >> 3;
  int c7 = ((l & 7) ^ l3) * 8;
  const short* aA = A + (size_t)(m0 + w * 8 + l3) * K + c7;
  const short* aB = Bt + (size_t)(n0 + w * 8 + l3) * K + c7;
  int wm = (w & 1) * 64, wn = (w >> 1) * 64;
  int sw = lm & 7;

  for (int kt = 0; kt < K; kt += 64) {
#pragma unroll
    for (int j = 0; j < 4; j++) {
      GLL16(aA + (size_t)(j * 32) * K, As + (j * 32 + w * 8) * 64);
      GLL16(aB + (size_t)(j * 32) * K, Bs + (j * 32 + w * 8) * 64);
    }
    aA += 64;
    aB += 64;
    __syncthreads();
#pragma unroll
    for (int kk = 0; kk < 2; kk++) {
      int rdoff = ((kk * 4 + lq) ^ sw) * 8;
      short8 af[4], bfr[4];
#pragma unroll
      for (int mi = 0; mi < 4; mi++)
        af[mi] = *(const short8*)&As[(wm + mi * 16 + lm) * 64 + rdoff];
#pragma unroll
      for (int ni = 0; ni < 4; ni++)
        bfr[ni] = *(const short8*)&Bs[(wn + ni * 16 + lm) * 64 + rdoff];
#pragma unroll
      for (int mi = 0; mi < 4; mi++)
#pragma unroll
        for (int ni = 0; ni < 4; ni++)
          acc[mi][ni] = __builtin_amdgcn_mfma_f32_16x16x32_bf16(af[mi], bfr[ni],
                                                                acc[mi][ni], 0, 0, 0);
    }
    __syncthreads();
  }

#pragma unroll
  for (int mi = 0; mi < 4; mi++) {
#pragma unroll
    for (int ni = 0; ni < 4; ni++) {
      int col = n0 + wn + ni * 16 + lm;
      float bcol = bias[col];
#pragma unroll
      for (int r = 0; r < 4; r++) {
        int row = m0 + wm + mi * 16 + lq * 4 + r;
        float v = acc[mi][ni][r] + bcol;
        size_t idx = (size_t)row * N + col;
        if (MODE == 0) {
          outb[idx] = f2bf(v);
        } else if (MODE == 1) {
          outf[idx] = v + res[idx];
        } else {
          float vc = v + 0.044715f * v * v * v;
          float e = __builtin_amdgcn_exp2f(2.302265246314f * vc);
          float ge = v * e * __builtin_amdgcn_rcpf(e + 1.0f);
          outb[idx] = f2bf(ge);
        }
      }
    }
  }
}

// Persistent GEMM stage for the mega-kernel: XCD-banded tile walk, 96 slots/XCD.
template <int MODE>
__device__ __forceinline__ void dev_gemm_stage(
    const short* A, const short* Bt, const float* bias, const float* res,
    float* outf, short* outb, int M, int N, int K, char* smem, int b0) {
  int nx = N >> 7, ny = M >> 7;
  int per_xcd = (nx * ny) >> 3;
  int rows_per = ny >> 3;
  int xcd = b0 & 7, slot = b0 >> 3;
  for (int k2 = slot; k2 < per_xcd; k2 += 96) {
    int mt = xcd * rows_per + k2 / nx;
    int nt = k2 % nx;
    dev_gemm_tile<MODE>(A, Bt, bias, res, outf, outb, N, K, mt << 7, nt << 7, smem);
  }
}

__device__ __forceinline__ void dev_vtrans(int item, const short* qkv,
                                           short* vt, char* smem) {
  short (*Ls)[72] = (short (*)[72])smem;
  int t = threadIdx.x;
  int s0 = (item & 31) * 64;
  int bh = item >> 5;
  int b = bh >> 4, h = bh & 15;
  const short* vsrc = qkv + (size_t)b * SS * 3072 + 2048 + h * 64;
#pragma unroll
  for (int it = 0; it < 2; it++) {
    int idx = it * 256 + t;
    int sr = idx >> 3, ch = idx & 7;
    *(short8*)&Ls[sr][ch * 8] =
        *(const short8*)&vsrc[(size_t)(s0 + sr) * 3072 + ch * 8];
  }
  __syncthreads();
  int d = t >> 2, sb = (t & 3) * 16;
  short tmp[16];
#pragma unroll
  for (int j = 0; j < 16; j++) tmp[j] = Ls[sb + j][d];
  short8* dst = (short8*)&vt[(size_t)bh * DK * SS + (size_t)d * SS + s0 + sb];
  dst[0] = *(short8*)&tmp[0];
  dst[1] = *(short8*)&tmp[8];
  __syncthreads();
}

// Flash attention item (causal, S^T form, scale folded into q, l via MFMA).
__device__ __forceinline__ void dev_attn(int item, const short* qkv,
                                         const short* vt, short* o, char* smem) {
  short* Qs = (short*)smem;        // 128*64
  short* Ks = Qs + 128 * 64;       // 64*64
  short* Vs = Ks + 64 * 64;        // 80*64 (rows 64..79 const)
  short* Ps = Vs + 80 * 64;        // 128*72
  int t = threadIdx.x, w = t >> 6, l = t & 63;
  int bh = item & 63;
  int qi = 15 - (item >> 6);
  int b = bh >> 4, h = bh & 15;
  const short* qbase = qkv + (size_t)b * SS * 3072 + h * DK;
  const short* kbase = qbase + 1024;
  const short* vbase = vt + (size_t)bh * DK * SS;
  short* obase = o + (size_t)b * SS * D_MODEL + h * DK;
  int l7 = l & 7, l3 = l >> 3;
  int c7 = (l7 ^ l3) * 8;
  int lm = l & 15, lq = l >> 4;
  int swq = lm & 7;
  int q0 = qi * 128;

  __syncthreads();  // protect smem from previous stage/item readers
  {
    int r = 64 + (t >> 4);
    int c = (t & 15) * 4;
    short val = (r == 64) ? (short)0x3F80 : (short)0;
    short4v vv = {val, val, val, val};
    *(short4v*)&Vs[r * 64 + c] = vv;
  }
#pragma unroll
  for (int j = 0; j < 4; j++) {
    int r8 = w * 32 + j * 8;
    GLL16(qbase + (size_t)(q0 + r8 + l3) * 3072 + c7, Qs + r8 * 64);
  }
  __syncthreads();
  short8 aq[2][2];
#pragma unroll
  for (int m = 0; m < 2; m++)
#pragma unroll
    for (int hf = 0; hf < 2; hf++)
      aq[m][hf] = *(const short8*)&Qs[(w * 32 + m * 16 + lm) * 64 +
                                      ((hf * 4 + lq) ^ swq) * 8];

  floatx4 accO[2][4] = {};
  floatx4 accL[2] = {};
  int qrow[2] = {q0 + w * 32 + lm, q0 + w * 32 + 16 + lm};
  int wrow_min = q0 + w * 32;
  int wrow_max = wrow_min + 31;
  int ntile = 2 * qi + 2;
  for (int kt = 0; kt < ntile; kt++) {
    int k0 = kt * 64;
    __syncthreads();
#pragma unroll
    for (int j = 0; j < 2; j++) {
      int r8 = (w * 2 + j) * 8;
      GLL16(kbase + (size_t)(k0 + r8 + l3) * 3072 + c7, Ks + r8 * 64);
      GLL16(vbase + (size_t)(r8 + l3) * SS + k0 + c7, Vs + r8 * 64);
    }
    __syncthreads();

    if (k0 <= wrow_max) {
      floatx4 sc[4][2];
#pragma unroll
      for (int sb = 0; sb < 4; sb++) {
        short8 k0f = *(const short8*)&Ks[(sb * 16 + lm) * 64 + (lq ^ swq) * 8];
        short8 k1f =
            *(const short8*)&Ks[(sb * 16 + lm) * 64 + ((4 + lq) ^ swq) * 8];
#pragma unroll
        for (int m = 0; m < 2; m++) {
          floatx4 z = {};
          z = __builtin_amdgcn_mfma_f32_16x16x32_bf16(k0f, aq[m][0], z, 0, 0, 0);
          z = __builtin_amdgcn_mfma_f32_16x16x32_bf16(k1f, aq[m][1], z, 0, 0, 0);
          sc[sb][m] = z;
        }
      }
      if (k0 + 63 <= wrow_min) {
#pragma unroll
        for (int sb = 0; sb < 4; sb++)
#pragma unroll
          for (int m = 0; m < 2; m++)
#pragma unroll
            for (int r = 0; r < 4; r++)
              sc[sb][m][r] = __builtin_amdgcn_exp2f(sc[sb][m][r]);
      } else {
#pragma unroll
        for (int sb = 0; sb < 4; sb++) {
          int sbase = k0 + sb * 16 + lq * 4;
#pragma unroll
          for (int m = 0; m < 2; m++)
#pragma unroll
            for (int r = 0; r < 4; r++)
              sc[sb][m][r] = (sbase + r > qrow[m])
                                 ? 0.f
                                 : __builtin_amdgcn_exp2f(sc[sb][m][r]);
        }
      }
#pragma unroll
      for (int m = 0; m < 2; m++)
#pragma unroll
        for (int sb = 0; sb < 4; sb++) {
          union { float f; unsigned int u; } c0, c1, c2, c3;
          c0.f = sc[sb][m][0]; c1.f = sc[sb][m][1];
          c2.f = sc[sb][m][2]; c3.f = sc[sb][m][3];
          uint2v pk;
          pk.x = __builtin_amdgcn_perm(c1.u, c0.u, 0x07060302u);
          pk.y = __builtin_amdgcn_perm(c3.u, c2.u, 0x07060302u);
          *(uint2v*)&Ps[(w * 32 + m * 16 + lm) * 72 + sb * 16 + lq * 4] = pk;
        }
      short8 pa[2][2];
#pragma unroll
      for (int m = 0; m < 2; m++)
#pragma unroll
        for (int hf = 0; hf < 2; hf++)
          pa[m][hf] =
              *(const short8*)&Ps[(w * 32 + m * 16 + lm) * 72 + hf * 32 + lq * 8];
      short8 o0 = *(const short8*)&Vs[(64 + lm) * 64 + (lq ^ swq) * 8];
      short8 o1 = *(const short8*)&Vs[(64 + lm) * 64 + ((4 + lq) ^ swq) * 8];
#pragma unroll
      for (int m = 0; m < 2; m++) {
        accL[m] = __builtin_amdgcn_mfma_f32_16x16x32_bf16(pa[m][0], o0, accL[m], 0, 0, 0);
        accL[m] = __builtin_amdgcn_mfma_f32_16x16x32_bf16(pa[m][1], o1, accL[m], 0, 0, 0);
      }
#pragma unroll
      for (int nb = 0; nb < 4; nb++) {
        short8 v0f = *(const short8*)&Vs[(nb * 16 + lm) * 64 + (lq ^ swq) * 8];
        short8 v1f =
            *(const short8*)&Vs[(nb * 16 + lm) * 64 + ((4 + lq) ^ swq) * 8];
#pragma unroll
        for (int m = 0; m < 2; m++) {
          accO[m][nb] = __builtin_amdgcn_mfma_f32_16x16x32_bf16(pa[m][0], v0f,
                                                                accO[m][nb], 0, 0, 0);
          accO[m][nb] = __builtin_amdgcn_mfma_f32_16x16x32_bf16(pa[m][1], v1f,
                                                                accO[m][nb], 0, 0, 0);
        }
      }
    }
  }
#pragma unroll
  for (int m = 0; m < 2; m++) {
#pragma unroll
    for (int r = 0; r < 4; r++) {
      float lv = __shfl(accL[m][r], l & 48, 64);
      float invr = __builtin_amdgcn_rcpf(lv);
      int rowg = q0 + w * 32 + m * 16 + lq * 4 + r;
#pragma unroll
      for (int nb = 0; nb < 4; nb++)
        obase[(size_t)rowg * D_MODEL + nb * 16 + lm] = f2bf(accO[m][nb][r] * invr);
    }
  }
}

// =========================== mega cooperative kernel ========================
struct MegaArgs {
  const float *x, *Wq, *bq, *Wk, *bk, *Wv, *bv, *Wo, *bo;
  const float *ln1g, *ln1b, *ln2g, *ln2b, *W1, *b1, *W2, *b2;
  float* out;
  short *wqkv_t, *wo_t, *w1_t, *w2_t;
  float* bqkv;
  short *h_bf, *qkvb, *vtg, *ffn1;
};

__global__ __launch_bounds__(256, 3) void mega_kernel(MegaArgs a) {
  __shared__ __align__(16) char smem[53248];
  cg::grid_group grid = cg::this_grid();
  int b0 = blockIdx.x;

  // S1: weight convert (+bias concat) fused with LN1 (independent work).
  for (int id = b0; id < 3073 + NTOK; id += NBLK) {
    if (id < 3073)
      dev_wconv(id, a.Wq, a.Wk, a.Wv, a.Wo, a.W1, a.W2, a.bq, a.bk, a.bv,
                a.wqkv_t, a.wo_t, a.w1_t, a.w2_t, a.bqkv, smem);
    else
      dev_ln_row(id - 3073, a.x, a.ln1g, a.ln1b, a.h_bf, smem);
    __syncthreads();
  }
  grid.sync();
  // S2: fused QKV GEMM
  dev_gemm_stage<0>(a.h_bf, a.wqkv_t, a.bqkv, nullptr, nullptr, a.qkvb,
                    NTOK, 3072, 1024, smem, b0);
  grid.sync();
  // S3: V transpose
  for (int id = b0; id < 2048; id += NBLK)
    dev_vtrans(id, a.qkvb, a.vtg, smem);
  grid.sync();
  // S4: attention (1024 items; blocks >=512 take a heavy+light pair)
  dev_attn(b0, a.qkvb, a.vtg, a.h_bf, smem);
  if (b0 >= 512) dev_attn(1535 - b0, a.qkvb, a.vtg, a.h_bf, smem);
  grid.sync();
  // S5: O-proj + residual -> out (fp32)
  dev_gemm_stage<1>(a.h_bf, a.wo_t, a.bo, a.x, a.out, nullptr,
                    NTOK, 1024, 1024, smem, b0);
  grid.sync();
  // S6: LN2
  for (int id = b0; id < NTOK; id += NBLK) {
    dev_ln_row(id, a.out, a.ln2g, a.ln2b, a.h_bf, smem);
    __syncthreads();
  }
  grid.sync();
  // S7: FFN1 + GELU
  dev_gemm_stage<2>(a.h_bf, a.w1_t, a.b1, nullptr, nullptr, a.ffn1,
                    NTOK, 4096, 1024, smem, b0);
  grid.sync();
  // S8: FFN2 + residual -> out
  dev_gemm_stage<1>(a.ffn1, a.w2_t, a.b2, a.out, a.out, nullptr,
                    NTOK, 1024, 4096, smem, b0);
}

// =========================== fallback kernels (R8 path) =====================
__global__ __launch_bounds__(256) void ln_kernel(const float* x, const float* g,
                                                 const float* b, short* out) {
  __shared__ __align__(16) char smem[64];
  dev_ln_row(blockIdx.x, x, g, b, out, smem);
}

__global__ __launch_bounds__(256) void wconvert_all(
    const float* Wq, const float* Wk, const float* Wv, const float* Wo,
    const float* W1, const float* W2, const float* bq, const float* bk,
    const float* bv, short* wqkv_t, short* wo_t, short* w1_t, short* w2_t,
    float* bqkv) {
  __shared__ __align__(16) char smem[64 * 65 * 4];
  dev_wconv(blockIdx.x, Wq, Wk, Wv, Wo, W1, W2, bq, bk, bv, wqkv_t, wo_t, w1_t,
            w2_t, bqkv, smem);
}

template <int MODE>
__global__ __launch_bounds__(256, 4) void gemm_bt(const short* A, const short* Bt,
                                                  const float* bias,
                                                  const float* res, float* outf,
                                                  short* outb, int M, int N, int K) {
  __shared__ __align__(16) char smem[32768];
  int nx = gridDim.x;
  int id = blockIdx.y * nx + blockIdx.x;
  int xcd = id & 7;
  int k = id >> 3;
  int rows_per = gridDim.y >> 3;
  int mt = xcd * rows_per + k / nx;
  int nt = k - (k / nx) * nx;
  dev_gemm_tile<MODE>(A, Bt, bias, res, outf, outb, N, K, mt * 128, nt * 128, smem);
}

__global__ __launch_bounds__(256) void vtrans(const short* qkv, short* vt) {
  __shared__ __align__(16) char smem[64 * 72 * 2];
  dev_vtrans(blockIdx.y * 32 + blockIdx.x, qkv, vt, smem);
}

__global__ __launch_bounds__(256, 3) void attn_kernel(const short* qkv,
                                                      const short* vt, short* o) {
  __shared__ __align__(16) char smem[53248];
  dev_attn(blockIdx.y * 64 + blockIdx.x, qkv, vt, o, smem);
}

// ------------------------------ launch ------------------------------
extern "C" void kernel_launch(void* const* d_in, const int* in_sizes, int n_in,
                              void* d_out, int out_size, void* d_ws, size_t ws_size,
                              hipStream_t stream) {
  const float* x = (const float*)d_in[0];
  const float* Wq = (const float*)d_in[1];
  const float* bq = (const float*)d_in[2];
  const float* Wk = (const float*)d_in[3];
  const float* bk = (const float*)d_in[4];
  const float* Wv = (const float*)d_in[5];
  const float* bv = (const float*)d_in[6];
  const float* Wo = (const float*)d_in[7];
  const float* bo = (const float*)d_in[8];
  const float* ln1g = (const float*)d_in[9];
  const float* ln1b = (const float*)d_in[10];
  const float* ln2g = (const float*)d_in[11];
  const float* ln2b = (const float*)d_in[12];
  const float* W1 = (const float*)d_in[13];
  const float* b1 = (const float*)d_in[14];
  const float* W2 = (const float*)d_in[15];
  const float* b2 = (const float*)d_in[16];
  float* out = (float*)d_out;

  short* wqkv_t = (short*)d_ws;                     // [3072][1024]
  short* wo_t = wqkv_t + 3072 * 1024;               // [1024][1024]
  short* w1_t = wo_t + 1024 * 1024;                 // [4096][1024]
  short* w2_t = w1_t + 4096 * 1024;                 // [1024][4096]
  float* bqkv = (float*)(w2_t + 1024 * 4096);       // [3072]
  short* h_bf = (short*)(bqkv + 3072);              // [8192][1024]
  short* qkvb = h_bf + (size_t)NTOK * D_MODEL;      // [8192][3072]
  short* vtg = qkvb + (size_t)NTOK * 3072;          // [64][64][2048]
  short* ffn1 = qkvb;                               // overlay

  MegaArgs a;
  a.x = x; a.Wq = Wq; a.bq = bq; a.Wk = Wk; a.bk = bk; a.Wv = Wv; a.bv = bv;
  a.Wo = Wo; a.bo = bo; a.ln1g = ln1g; a.ln1b = ln1b; a.ln2g = ln2g;
  a.ln2b = ln2b; a.W1 = W1; a.b1 = b1; a.W2 = W2; a.b2 = b2; a.out = out;
  a.wqkv_t = wqkv_t; a.wo_t = wo_t; a.w1_t = w1_t; a.w2_t = w2_t;
  a.bqkv = bqkv; a.h_bf = h_bf; a.qkvb = qkvb; a.vtg = vtg; a.ffn1 = ffn1;
  void* kp[1] = {&a};
  hipError_t err = hipLaunchCooperativeKernel((void*)mega_kernel, dim3(NBLK),
                                              dim3(256), kp, 0, stream);
  if (err == hipSuccess) return;

  // -------- fallback: R8 multi-kernel pipeline --------
  wconvert_all<<<3073, 256, 0, stream>>>(Wq, Wk, Wv, Wo, W1, W2, bq, bk, bv,
                                         wqkv_t, wo_t, w1_t, w2_t, bqkv);
  ln_kernel<<<NTOK, 256, 0, stream>>>(x, ln1g, ln1b, h_bf);
  gemm_bt<0><<<dim3(24, 64), 256, 0, stream>>>(h_bf, wqkv_t, bqkv, nullptr,
                                               nullptr, qkvb, NTOK, 3072, 1024);
  vtrans<<<dim3(32, 64), 256, 0, stream>>>(qkvb, vtg);
  attn_kernel<<<dim3(64, 16), 256, 0, stream>>>(qkvb, vtg, h_bf);
  gemm_bt<1><<<dim3(8, 64), 256, 0, stream>>>(h_bf, wo_t, bo, x, out, nullptr,
                                              NTOK, 1024, 1024);
  ln_kernel<<<NTOK, 256, 0, stream>>>(out, ln2g, ln2b, h_bf);
  gemm_bt<2><<<dim3(32, 64), 256, 0, stream>>>(h_bf, w1_t, b1, nullptr, nullptr,
                                               ffn1, NTOK, 4096, 1024);
  gemm_bt<1><<<dim3(8, 64), 256, 0, stream>>>(ffn1, w2_t, b2, out, out, nullptr,
                                              NTOK, 1024, 4096);
}

// Round 10
// 451.582 us; speedup vs baseline: 2.5114x; 2.5114x over previous
//
#include <hip/hip_runtime.h>
#include <hip/hip_bf16.h>
#include <math.h>

typedef __attribute__((ext_vector_type(8))) short short8;
typedef __attribute__((ext_vector_type(4))) float floatx4;
typedef __attribute__((ext_vector_type(4))) short short4v;
typedef __attribute__((ext_vector_type(2))) unsigned int uint2v;

#define D_MODEL 1024
#define N_HEADS 16
#define DK 64
#define D_FF 4096
#define BB 4
#define SS 2048
#define NTOK (BB * SS) /* 8192 */
#define LN_EPS 1e-5f
#define SCL 0.18033688011112042f /* 0.125 * log2(e), folded into Wq/bq */

static __device__ __forceinline__ short f2bf(float f) {
  union { float f; unsigned int u; } v;
  v.f = f;
  unsigned int u = v.u;
  unsigned int r = u + 0x7fffu + ((u >> 16) & 1u); // round-to-nearest-even
  return (short)(r >> 16);
}

#define GLL16(g, l)                                                            \
  __builtin_amdgcn_global_load_lds(                                            \
      (const __attribute__((address_space(1))) void*)(g),                      \
      (__attribute__((address_space(3))) void*)(l), 16, 0, 0)

// ---------------- LayerNorm row helper: fp32 row -> bf16 row ----------------
__device__ __forceinline__ void ln_row(int row, const float* __restrict__ x,
                                       const float* __restrict__ g,
                                       const float* __restrict__ b,
                                       short* __restrict__ out, float* red) {
  int t = threadIdx.x;
  const float4* rp = (const float4*)(x + (size_t)row * D_MODEL);
  float4 v = rp[t];
  float s = v.x + v.y + v.z + v.w;
  float ss = v.x * v.x + v.y * v.y + v.z * v.z + v.w * v.w;
#pragma unroll
  for (int off = 32; off >= 1; off >>= 1) {
    s += __shfl_xor(s, off, 64);
    ss += __shfl_xor(ss, off, 64);
  }
  int wv = t >> 6;
  if ((t & 63) == 0) { red[wv] = s; red[wv + 4] = ss; }
  __syncthreads();
  s = red[0] + red[1] + red[2] + red[3];
  ss = red[4] + red[5] + red[6] + red[7];
  float mu = s * (1.0f / D_MODEL);
  float var = ss * (1.0f / D_MODEL) - mu * mu;
  float rstd = rsqrtf(var + LN_EPS);
  float4 gv = ((const float4*)g)[t];
  float4 bv = ((const float4*)b)[t];
  short4v o;
  o.x = f2bf((v.x - mu) * rstd * gv.x + bv.x);
  o.y = f2bf((v.y - mu) * rstd * gv.y + bv.y);
  o.z = f2bf((v.z - mu) * rstd * gv.z + bv.z);
  o.w = f2bf((v.w - mu) * rstd * gv.w + bv.w);
  *(short4v*)(out + (size_t)row * D_MODEL + t * 4) = o;
}

__global__ __launch_bounds__(256) void ln_kernel(const float* __restrict__ x,
                                                 const float* __restrict__ g,
                                                 const float* __restrict__ b,
                                                 short* __restrict__ out) {
  __shared__ float red[8];
  ln_row(blockIdx.x, x, g, b, out, red);
}

// ---- Prep: weight convert+transpose + bias concat + LN1, one launch ----
// blocks 0..1023: Wq/Wk/Wv/Wo; 1024..2047: W1; 2048..3071: W2; 3072: biases;
// 3073..3073+8191: LN1 rows. Wq/bq pre-scaled by SCL.
__global__ __launch_bounds__(256) void prep_kernel(
    const float* __restrict__ Wq, const float* __restrict__ Wk,
    const float* __restrict__ Wv, const float* __restrict__ Wo,
    const float* __restrict__ W1, const float* __restrict__ W2,
    const float* __restrict__ bq, const float* __restrict__ bk,
    const float* __restrict__ bv, const float* __restrict__ x,
    const float* __restrict__ ln1g, const float* __restrict__ ln1b,
    short* __restrict__ wqkv_t, short* __restrict__ wo_t,
    short* __restrict__ w1_t, short* __restrict__ w2_t,
    float* __restrict__ bqkv, short* __restrict__ h_bf) {
  __shared__ __align__(16) float smem[64 * 65];
  int id = blockIdx.x;
  int t = threadIdx.x;
  if (id >= 3073) {
    ln_row(id - 3073, x, ln1g, ln1b, h_bf, smem);
    return;
  }
  if (id == 3072) {
    for (int i = t; i < 1024; i += 256) {
      bqkv[i] = bq[i] * SCL;
      bqkv[1024 + i] = bk[i];
      bqkv[2048 + i] = bv[i];
    }
    return;
  }
  float (*tile)[65] = (float (*)[65])smem;
  const float* W;
  short* Wt;
  int K, N, tid;
  float scale = 1.0f;
  if (id < 1024) {
    int wsel = id >> 8;
    tid = id & 255;
    K = 1024; N = 1024;
    W = wsel == 0 ? Wq : wsel == 1 ? Wk : wsel == 2 ? Wv : Wo;
    Wt = wsel < 3 ? wqkv_t + (size_t)wsel * 1024 * 1024 : wo_t;
    if (wsel == 0) scale = SCL;
  } else if (id < 2048) {
    tid = id - 1024; K = 1024; N = 4096; W = W1; Wt = w1_t;
  } else {
    tid = id - 2048; K = 4096; N = 1024; W = W2; Wt = w2_t;
  }
  int ntn = N >> 6;
  int n0 = (tid % ntn) * 64, k0 = (tid / ntn) * 64;
  int c = t & 63, r0 = t >> 6;
#pragma unroll
  for (int i = 0; i < 16; i++) {
    int r = r0 + i * 4;
    tile[r][c] = W[(size_t)(k0 + r) * N + n0 + c];
  }
  __syncthreads();
#pragma unroll
  for (int i = 0; i < 16; i++) {
    int r = r0 + i * 4;
    Wt[(size_t)(n0 + r) * K + k0 + c] = f2bf(tile[c][r] * scale);
  }
}

// ---------------- GEMM: C[M,N] = A[M,K](bf16) x Bt[N,K](bf16) + bias -------------
// BK=64 rows span all 32 banks + XOR-8 swizzle; XCD-aware remap for A-reuse in L2.
// MODE 0: +bias -> bf16; MODE 1: +bias +res(fp32) -> fp32; MODE 2: GELU -> bf16;
// MODE 3: split-K fp32 atomicAdd into outf (bias only on blockIdx.z==0).
template <int MODE>
__global__ __launch_bounds__(256, 4) void gemm_bt(const short* __restrict__ A,
                                                  const short* __restrict__ Bt,
                                                  const float* __restrict__ bias,
                                                  const float* __restrict__ res,
                                                  float* __restrict__ outf,
                                                  short* __restrict__ outb,
                                                  int M, int N, int Kloop,
                                                  int ldK) {
  __shared__ short As[128 * 64];
  __shared__ short Bs[128 * 64];
  int t = threadIdx.x;
  int w = t >> 6, l = t & 63;
  int lm = l & 15, lq = l >> 4;
  int nx = gridDim.x;
  int id = blockIdx.y * nx + blockIdx.x;
  int xcd = id & 7;
  int k = id >> 3;
  int rows_per = gridDim.y >> 3;
  int mt = xcd * rows_per + k / nx;
  int nt = k - (k / nx) * nx;
  int m0 = mt * 128, n0 = nt * 128;
  int kz = blockIdx.z;
  const short* Az = A + (size_t)kz * Kloop;
  const short* Btz = Bt + (size_t)kz * Kloop;
  floatx4 acc[4][4] = {};
  int l3 = l >> 3;
  int c7 = ((l & 7) ^ l3) * 8;
  const short* aA = Az + (size_t)(m0 + w * 8 + l3) * ldK + c7;
  const short* aB = Btz + (size_t)(n0 + w * 8 + l3) * ldK + c7;
  int wm = (w & 1) * 64, wn = (w >> 1) * 64;
  int sw = lm & 7;

  for (int kt = 0; kt < Kloop; kt += 64) {
#pragma unroll
    for (int j = 0; j < 4; j++) {
      GLL16(aA + (size_t)(j * 32) * ldK, As + (j * 32 + w * 8) * 64);
      GLL16(aB + (size_t)(j * 32) * ldK, Bs + (j * 32 + w * 8) * 64);
    }
    aA += 64;
    aB += 64;
    __syncthreads();
#pragma unroll
    for (int kk = 0; kk < 2; kk++) {
      int rdoff = ((kk * 4 + lq) ^ sw) * 8;
      short8 af[4], bfr[4];
#pragma unroll
      for (int mi = 0; mi < 4; mi++)
        af[mi] = *(const short8*)&As[(wm + mi * 16 + lm) * 64 + rdoff];
#pragma unroll
      for (int ni = 0; ni < 4; ni++)
        bfr[ni] = *(const short8*)&Bs[(wn + ni * 16 + lm) * 64 + rdoff];
#pragma unroll
      for (int mi = 0; mi < 4; mi++)
#pragma unroll
        for (int ni = 0; ni < 4; ni++)
          acc[mi][ni] = __builtin_amdgcn_mfma_f32_16x16x32_bf16(af[mi], bfr[ni],
                                                                acc[mi][ni], 0, 0, 0);
    }
    __syncthreads();
  }

  bool addb = (MODE != 3) || (kz == 0);
#pragma unroll
  for (int mi = 0; mi < 4; mi++) {
#pragma unroll
    for (int ni = 0; ni < 4; ni++) {
      int col = n0 + wn + ni * 16 + lm;
      float bcol = addb ? bias[col] : 0.0f;
#pragma unroll
      for (int r = 0; r < 4; r++) {
        int row = m0 + wm + mi * 16 + lq * 4 + r;
        float v = acc[mi][ni][r] + bcol;
        size_t idx = (size_t)row * N + col;
        if (MODE == 0) {
          outb[idx] = f2bf(v);
        } else if (MODE == 1) {
          outf[idx] = v + res[idx];
        } else if (MODE == 2) {
          float vc = v + 0.044715f * v * v * v;
          float e = __builtin_amdgcn_exp2f(2.302265246314f * vc);
          float ge = v * e * __builtin_amdgcn_rcpf(e + 1.0f);
          outb[idx] = f2bf(ge);
        } else {
          atomicAdd(&outf[idx], v);
        }
      }
    }
  }
}

// ------------- V transpose prepass: qkv v-cols -> vt[bh][d][s] -------------
__global__ __launch_bounds__(256) void vtrans(const short* __restrict__ qkv,
                                              short* __restrict__ vt) {
  __shared__ short Ls[64][72];
  int t = threadIdx.x;
  int s0 = blockIdx.x * 64;
  int bh = blockIdx.y;
  int b = bh >> 4, h = bh & 15;
  const short* vsrc = qkv + (size_t)b * SS * 3072 + 2048 + h * 64;
#pragma unroll
  for (int it = 0; it < 2; it++) {
    int idx = it * 256 + t;
    int sr = idx >> 3, ch = idx & 7;
    *(short8*)&Ls[sr][ch * 8] =
        *(const short8*)&vsrc[(size_t)(s0 + sr) * 3072 + ch * 8];
  }
  __syncthreads();
  int d = t >> 2, sb = (t & 3) * 16;
  short tmp[16];
#pragma unroll
  for (int j = 0; j < 16; j++) tmp[j] = Ls[sb + j][d];
  short8* dst = (short8*)&vt[(size_t)bh * DK * SS + (size_t)d * SS + s0 + sb];
  dst[0] = *(short8*)&tmp[0];
  dst[1] = *(short8*)&tmp[8];
}

// ------- Flash attention (causal): S^T form, scale folded into q, l via MFMA -------
__global__ __launch_bounds__(256, 3) void attn_kernel(const short* __restrict__ qkv,
                                                      const short* __restrict__ vt,
                                                      short* __restrict__ o) {
  __shared__ short Qs[128 * 64];   // 16 KB, swizzled chunks
  __shared__ short Ks[64 * 64];    // 8 KB, swizzled
  __shared__ short Vs[80 * 64];    // 10 KB: rows 0-63 = V^T tile; row 64 = ones,
                                   // rows 65-79 = 0 (constant, swizzle-invariant)
  __shared__ short Ps[128 * 72];   // 18 KB, P[q][s] padded stride 72
  int t = threadIdx.x, w = t >> 6, l = t & 63;
  int bh = blockIdx.x;
  int qi = 15 - blockIdx.y;  // largest-work blocks first
  int b = bh >> 4, h = bh & 15;
  const short* qbase = qkv + (size_t)b * SS * 3072 + h * DK;
  const short* kbase = qbase + 1024;
  const short* vbase = vt + (size_t)bh * DK * SS;
  short* obase = o + (size_t)b * SS * D_MODEL + h * DK;
  int l7 = l & 7, l3 = l >> 3;
  int c7 = (l7 ^ l3) * 8;
  int lm = l & 15, lq = l >> 4;
  int swq = lm & 7;
  int q0 = qi * 128;

  {
    int r = 64 + (t >> 4);
    int c = (t & 15) * 4;
    short val = (r == 64) ? (short)0x3F80 : (short)0;
    short4v vv = {val, val, val, val};
    *(short4v*)&Vs[r * 64 + c] = vv;
  }
#pragma unroll
  for (int j = 0; j < 4; j++) {
    int r8 = w * 32 + j * 8;
    GLL16(qbase + (size_t)(q0 + r8 + l3) * 3072 + c7, Qs + r8 * 64);
  }
  __syncthreads();
  short8 aq[2][2];
#pragma unroll
  for (int m = 0; m < 2; m++)
#pragma unroll
    for (int hf = 0; hf < 2; hf++)
      aq[m][hf] = *(const short8*)&Qs[(w * 32 + m * 16 + lm) * 64 +
                                      ((hf * 4 + lq) ^ swq) * 8];

  floatx4 accO[2][4] = {};
  floatx4 accL[2] = {};  // P·ones: row-sums
  int qrow[2] = {q0 + w * 32 + lm, q0 + w * 32 + 16 + lm};
  int wrow_min = q0 + w * 32;
  int wrow_max = wrow_min + 31;
  int ntile = 2 * qi + 2;
  for (int kt = 0; kt < ntile; kt++) {
    int k0 = kt * 64;
    __syncthreads();
#pragma unroll
    for (int j = 0; j < 2; j++) {
      int r8 = (w * 2 + j) * 8;
      GLL16(kbase + (size_t)(k0 + r8 + l3) * 3072 + c7, Ks + r8 * 64);
      GLL16(vbase + (size_t)(r8 + l3) * SS + k0 + c7, Vs + r8 * 64);
    }
    __syncthreads();

    if (k0 <= wrow_max) {
      // ---- S^T = K·Q^T (scores pre-scaled via Wq) ----
      floatx4 sc[4][2];
#pragma unroll
      for (int sb = 0; sb < 4; sb++) {
        short8 k0f = *(const short8*)&Ks[(sb * 16 + lm) * 64 + (lq ^ swq) * 8];
        short8 k1f =
            *(const short8*)&Ks[(sb * 16 + lm) * 64 + ((4 + lq) ^ swq) * 8];
#pragma unroll
        for (int m = 0; m < 2; m++) {
          floatx4 z = {};
          z = __builtin_amdgcn_mfma_f32_16x16x32_bf16(k0f, aq[m][0], z, 0, 0, 0);
          z = __builtin_amdgcn_mfma_f32_16x16x32_bf16(k1f, aq[m][1], z, 0, 0, 0);
          sc[sb][m] = z;
        }
      }
      if (k0 + 63 <= wrow_min) {  // fully unmasked (wave-uniform)
#pragma unroll
        for (int sb = 0; sb < 4; sb++)
#pragma unroll
          for (int m = 0; m < 2; m++)
#pragma unroll
            for (int r = 0; r < 4; r++)
              sc[sb][m][r] = __builtin_amdgcn_exp2f(sc[sb][m][r]);
      } else {
#pragma unroll
        for (int sb = 0; sb < 4; sb++) {
          int sbase = k0 + sb * 16 + lq * 4;
#pragma unroll
          for (int m = 0; m < 2; m++)
#pragma unroll
            for (int r = 0; r < 4; r++)
              sc[sb][m][r] = (sbase + r > qrow[m])
                                 ? 0.f
                                 : __builtin_amdgcn_exp2f(sc[sb][m][r]);
        }
      }
      // ---- P: truncate+pack pairs via v_perm -> ds_write_b64 ----
#pragma unroll
      for (int m = 0; m < 2; m++)
#pragma unroll
        for (int sb = 0; sb < 4; sb++) {
          union { float f; unsigned int u; } c0, c1, c2, c3;
          c0.f = sc[sb][m][0]; c1.f = sc[sb][m][1];
          c2.f = sc[sb][m][2]; c3.f = sc[sb][m][3];
          uint2v pk;
          pk.x = __builtin_amdgcn_perm(c1.u, c0.u, 0x07060302u);
          pk.y = __builtin_amdgcn_perm(c3.u, c2.u, 0x07060302u);
          *(uint2v*)&Ps[(w * 32 + m * 16 + lm) * 72 + sb * 16 + lq * 4] = pk;
        }
      short8 pa[2][2];
#pragma unroll
      for (int m = 0; m < 2; m++)
#pragma unroll
        for (int hf = 0; hf < 2; hf++)
          pa[m][hf] =
              *(const short8*)&Ps[(w * 32 + m * 16 + lm) * 72 + hf * 32 + lq * 8];
      // ---- O = P·V, plus l = P·ones ----
      short8 o0 = *(const short8*)&Vs[(64 + lm) * 64 + (lq ^ swq) * 8];
      short8 o1 = *(const short8*)&Vs[(64 + lm) * 64 + ((4 + lq) ^ swq) * 8];
#pragma unroll
      for (int m = 0; m < 2; m++) {
        accL[m] = __builtin_amdgcn_mfma_f32_16x16x32_bf16(pa[m][0], o0, accL[m], 0, 0, 0);
        accL[m] = __builtin_amdgcn_mfma_f32_16x16x32_bf16(pa[m][1], o1, accL[m], 0, 0, 0);
      }
#pragma unroll
      for (int nb = 0; nb < 4; nb++) {
        short8 v0f = *(const short8*)&Vs[(nb * 16 + lm) * 64 + (lq ^ swq) * 8];
        short8 v1f =
            *(const short8*)&Vs[(nb * 16 + lm) * 64 + ((4 + lq) ^ swq) * 8];
#pragma unroll
        for (int m = 0; m < 2; m++) {
          accO[m][nb] = __builtin_amdgcn_mfma_f32_16x16x32_bf16(pa[m][0], v0f,
                                                                accO[m][nb], 0, 0, 0);
          accO[m][nb] = __builtin_amdgcn_mfma_f32_16x16x32_bf16(pa[m][1], v1f,
                                                                accO[m][nb], 0, 0, 0);
        }
      }
    }
  }
#pragma unroll
  for (int m = 0; m < 2; m++) {
#pragma unroll
    for (int r = 0; r < 4; r++) {
      float lv = __shfl(accL[m][r], l & 48, 64);
      float invr = __builtin_amdgcn_rcpf(lv);
      int rowg = q0 + w * 32 + m * 16 + lq * 4 + r;
#pragma unroll
      for (int nb = 0; nb < 4; nb++)
        obase[(size_t)rowg * D_MODEL + nb * 16 + lm] = f2bf(accO[m][nb][r] * invr);
    }
  }
}

// ------------------------------ launch ------------------------------
extern "C" void kernel_launch(void* const* d_in, const int* in_sizes, int n_in,
                              void* d_out, int out_size, void* d_ws, size_t ws_size,
                              hipStream_t stream) {
  const float* x = (const float*)d_in[0];
  const float* Wq = (const float*)d_in[1];
  const float* bq = (const float*)d_in[2];
  const float* Wk = (const float*)d_in[3];
  const float* bk = (const float*)d_in[4];
  const float* Wv = (const float*)d_in[5];
  const float* bv = (const float*)d_in[6];
  const float* Wo = (const float*)d_in[7];
  const float* bo = (const float*)d_in[8];
  const float* ln1g = (const float*)d_in[9];
  const float* ln1b = (const float*)d_in[10];
  const float* ln2g = (const float*)d_in[11];
  const float* ln2b = (const float*)d_in[12];
  const float* W1 = (const float*)d_in[13];
  const float* b1 = (const float*)d_in[14];
  const float* W2 = (const float*)d_in[15];
  const float* b2 = (const float*)d_in[16];
  float* out = (float*)d_out;

  short* wqkv_t = (short*)d_ws;                     // [3072][1024]
  short* wo_t = wqkv_t + 3072 * 1024;               // [1024][1024]
  short* w1_t = wo_t + 1024 * 1024;                 // [4096][1024]
  short* w2_t = w1_t + 4096 * 1024;                 // [1024][4096]
  float* bqkv = (float*)(w2_t + 1024 * 4096);       // [3072]
  short* h_bf = (short*)(bqkv + 3072);              // [8192][1024]
  short* qkvb = h_bf + (size_t)NTOK * D_MODEL;      // [8192][3072]
  short* vtg = qkvb + (size_t)NTOK * 3072;          // [64][64][2048]
  short* ffn1 = qkvb;                               // overlay

  // S1: weight convert + bias concat + LN1 (one launch)
  prep_kernel<<<3073 + NTOK, 256, 0, stream>>>(Wq, Wk, Wv, Wo, W1, W2, bq, bk,
                                               bv, x, ln1g, ln1b, wqkv_t, wo_t,
                                               w1_t, w2_t, bqkv, h_bf);
  // S2: fused QKV GEMM
  gemm_bt<0><<<dim3(24, 64), 256, 0, stream>>>(h_bf, wqkv_t, bqkv, nullptr,
                                               nullptr, qkvb, NTOK, 3072, 1024,
                                               1024);
  // S3: V transpose
  vtrans<<<dim3(SS / 64, 64), 256, 0, stream>>>(qkvb, vtg);
  // S4: attention
  attn_kernel<<<dim3(64, 16), 256, 0, stream>>>(qkvb, vtg, h_bf);
  // S5: O-proj + residual -> out (fp32)
  gemm_bt<1><<<dim3(8, 64), 256, 0, stream>>>(h_bf, wo_t, bo, x, out, nullptr,
                                              NTOK, 1024, 1024, 1024);
  // S6: LN2
  ln_kernel<<<NTOK, 256, 0, stream>>>(out, ln2g, ln2b, h_bf);
  // S7: FFN1 + GELU
  gemm_bt<2><<<dim3(32, 64), 256, 0, stream>>>(h_bf, w1_t, b1, nullptr, nullptr,
                                               ffn1, NTOK, 4096, 1024, 1024);
  // S8: FFN2 split-K=2, fp32 atomic accumulate onto out (which holds x2)
  gemm_bt<3><<<dim3(8, 64, 2), 256, 0, stream>>>(ffn1, w2_t, b2, nullptr, out,
                                                 nullptr, NTOK, 1024, 2048, 4096);
}